// Round 6
// baseline (290.321 us; speedup 1.0000x reference)
//
#include <hip/hip_runtime.h>

typedef __attribute__((ext_vector_type(8))) short short8;   // 8 x bf16 (4 VGPR)
typedef __attribute__((ext_vector_type(4))) float f32x4;

#define Bsz 4
#define Cin 256
#define Cout 256
#define Hh 64
#define Ww 64
#define HW 4096
#define NG 16
#define EPSV 1e-5f

#define CSTR 40    // col LDS row stride in ushorts (32 data + 8 pad)
#define WROWS 16   // staged input window rows [h-8, h+7]
#define PCH 32     // planes per chunk

static __device__ __forceinline__ unsigned f2bf(float f) {
    unsigned u = __float_as_uint(f);
    return (u + 0x7fffu + ((u >> 16) & 1u)) >> 16;   // RNE bf16
}

// ---------------------------------------------------------------------------
// Kernel 1: weight reorder w[o][c][kk] -> bf16 wtb[ks][o][32],  ks = kk*8 + c/32
// Also zeroes the GN stats accumulators.
// ---------------------------------------------------------------------------
__global__ void wt_kernel(const float* __restrict__ w, ushort* __restrict__ wtb,
                          float* __restrict__ stats) {
    const int i = blockIdx.x * 256 + threadIdx.x;      // over 589824
    if (blockIdx.x == 0 && threadIdx.x < 128) stats[threadIdx.x] = 0.f;
    if (i >= Cout * Cin * 9) return;
    const int o = i / (Cin * 9);
    const int rem = i % (Cin * 9);
    const int c = rem / 9, kk = rem % 9;
    const int ks = kk * 8 + (c >> 5);
    wtb[(ks * 256 + o) * 32 + (c & 31)] = (ushort)f2bf(w[i]);
}

// ---------------------------------------------------------------------------
// Kernel 2: fused deformable sampling + bf16 MFMA conv + GN partial stats.
// Block: 512 thr (8 waves) = one row (b,h): N=64 px, M=256 Co. Grid 256.
// Input window [h-8,h+7] x 32 planes staged in LDS (fp32, 128 KB);
// gathers hit LDS instead of L1. Rare out-of-window taps -> global fallback.
// ---------------------------------------------------------------------------
__launch_bounds__(512, 2)
__global__ void dcn_kernel(const float* __restrict__ in,
                           const float* __restrict__ offs,
                           const float* __restrict__ mask,
                           const ushort* __restrict__ wtb,
                           const float* __restrict__ bias,
                           float* __restrict__ out,
                           float* __restrict__ stats) {
    __shared__ float  s_in[PCH * WROWS * 64];   // 128 KB: [plane][slot][x]
    __shared__ ushort s_col[2][64 * CSTR];      // 10 KB col tile (bf16, dbuf)
    __shared__ int2   s_ta[9 * 64];             // window-relative corner addrs
    __shared__ float4 s_tw[9 * 64];             // folded pair weights

    const int t  = threadIdx.x;
    const int bx = blockIdx.x;
    // XCD swizzle: XCD (bx&7) serves one (batch, h-half) -> L2 window locality
    const int q  = bx & 7, r = bx >> 3;
    const int b  = q >> 1;
    const int h  = ((q & 1) << 5) | r;
    const int lane = t & 63;
    const int wv   = t >> 6;                    // wave 0..7 (m-strip 32*wv)
    const int quad = lane >> 4;
    const int l15  = lane & 15;
    const int gn   = lane;                      // gather pixel
    const int cg   = wv;                        // gather plane group (4 planes)

    const float* inb = in + (size_t)b * Cin * HW;

    // ---- issue chunk-0 staging loads (coalesced dwordx4) ----
    float4 st[16];
#pragma unroll
    for (int i = 0; i < 16; i++) {
        const int idx = i * 512 + t;
        const int p = idx >> 8, sl = (idx >> 4) & 15, qq = idx & 15;
        const int row = min(max(h - 8 + sl, 0), 63);
        st[i] = *(const float4*)(inb + (size_t)p * HW + row * 64 + qq * 4);
    }

    // ---- tap precompute: 9 kernel points x 64 pixels ----
    for (int j = t; j < 576; j += 512) {
        const int k = j >> 6, p = j & 63;
        const float* ob = offs + (size_t)b * 18 * HW + h * Ww + p;
        const float dy = ob[(2 * k) * HW];
        const float dx = ob[(2 * k + 1) * HW];
        const float m  = mask[((size_t)b * 9 + k) * HW + h * Ww + p];
        const float y = (float)h + (float)(k / 3 - 1) + dy;
        const float x = (float)p + (float)(k % 3 - 1) + dx;
        const float y0f = floorf(y), x0f = floorf(x);
        const float ly = y - y0f, lx = x - x0f;
        const float hy = 1.f - ly, hx = 1.f - lx;
        const int y0 = (int)y0f, x0 = (int)x0f;
        const int yc0 = min(max(y0, 0), 63);
        const int yc1 = min(max(y0 + 1, 0), 63);
        const int xb  = min(max(x0, 0), 62);
        float ax = 0.f, ay = 0.f;
        if (x0 == xb) {                       // x0 in [0,62]
            ax = hx; ay = lx;
        } else if (x0 < xb) {                 // x0 < 0
            ax = (x0 + 1 == 0) ? lx : 0.f;
        } else {                              // x0 > 62
            ay = (x0 == 63) ? hx : 0.f;       // x0>=64: both corners OOB
        }
        const float w0 = (y0 >= 0 && y0 < 64) ? m * hy : 0.f;
        const float w1 = (y0 + 1 >= 0 && y0 + 1 < 64) ? m * ly : 0.f;
        const int s0 = yc0 - (h - 8), s1 = yc1 - (h - 8);
        int2 ta;
        if (s0 >= 0 && s0 < WROWS && s1 >= 0 && s1 < WROWS)
            ta = make_int2(s0 * 64 + xb, s1 * 64 + xb);       // LDS path
        else
            ta = make_int2(-1 - (yc0 * 64 + xb), yc1 * 64 + xb); // global path
        s_ta[j] = ta;
        s_tw[j] = make_float4(w0 * ax, w0 * ay, w1 * ax, w1 * ay);
    }

    // ---- write chunk-0 staging to LDS ----
#pragma unroll
    for (int i = 0; i < 16; i++) {
        const int idx = i * 512 + t;
        const int p = idx >> 8, sl = (idx >> 4) & 15, qq = idx & 15;
        *(float4*)&s_in[p * 1024 + sl * 64 + qq * 4] = st[i];
    }
    __syncthreads();

    // ---- preload this pixel's 9 taps into registers ----
    int2   rta[9];
    float4 rtw[9];
#pragma unroll
    for (int k = 0; k < 9; k++) {
        rta[k] = s_ta[k * 64 + gn];
        rtw[k] = s_tw[k * 64 + gn];
    }

    f32x4 acc[2][4];
#pragma unroll
    for (int i = 0; i < 2; i++)
#pragma unroll
        for (int nt = 0; nt < 4; nt++) acc[i][nt] = (f32x4){0.f, 0.f, 0.f, 0.f};

    // col write slot (XOR-swizzled groups of 8 to break 4-way write conflicts)
    const int colw_off = gn * CSTR + ((((cg >> 1) ^ (gn >> 4)) & 3) << 3) + ((cg & 1) << 2);

    int pbuf = 0;
#pragma unroll 1
    for (int c = 0; c < 8; c++) {
#pragma unroll 1
        for (int kk = 0; kk < 9; kk++) {
            const int ks = kk * 8 + c;
            // A-frags (coalesced 1KB/wave, L2-hot); consumed after barrier
            const ushort* wp = wtb + ((size_t)(ks * 256 + wv * 32 + l15)) * 32 + quad * 8;
            const short8 a0 = *(const short8*)wp;
            const short8 a1 = *(const short8*)(wp + 16 * 32);

            // gather 4 samples (planes cg*4..+3, pixel gn) from staged LDS
            float vv[4];
            const int2   ad = rta[kk];
            const float4 tw = rtw[kk];
            if (ad.x >= 0) {
#pragma unroll
                for (int j = 0; j < 4; j++) {
                    const float* pb = &s_in[(cg * 4 + j) * (WROWS * 64)];
                    vv[j] = tw.x * pb[ad.x] + tw.y * pb[ad.x + 1] +
                            tw.z * pb[ad.y] + tw.w * pb[ad.y + 1];
                }
            } else {                      // rare: out-of-window -> global
                const int gx0 = -1 - ad.x;
#pragma unroll
                for (int j = 0; j < 4; j++) {
                    const float* pb = inb + (size_t)(c * 32 + cg * 4 + j) * HW;
                    vv[j] = tw.x * pb[gx0] + tw.y * pb[gx0 + 1] +
                            tw.z * pb[ad.y] + tw.w * pb[ad.y + 1];
                }
            }

            // prefetch next chunk's staging loads during last tap step
            if (kk == 8 && c < 7) {
#pragma unroll
                for (int i = 0; i < 16; i++) {
                    const int idx = i * 512 + t;
                    const int p = idx >> 8, sl = (idx >> 4) & 15, qq = idx & 15;
                    const int row = min(max(h - 8 + sl, 0), 63);
                    st[i] = *(const float4*)(inb + (size_t)((c + 1) * 32 + p) * HW +
                                             row * 64 + qq * 4);
                }
            }

            // pack bf16 col slice + publish
            const unsigned pk0 = f2bf(vv[0]) | (f2bf(vv[1]) << 16);
            const unsigned pk1 = f2bf(vv[2]) | (f2bf(vv[3]) << 16);
            *(unsigned long long*)&s_col[pbuf][colw_off] =
                (unsigned long long)pk0 | ((unsigned long long)pk1 << 32);
            __syncthreads();

            // B-frags (swizzle-aware) + MFMA
            short8 bfr[4];
#pragma unroll
            for (int nt = 0; nt < 4; nt++)
                bfr[nt] = *(const short8*)&s_col[pbuf][(nt * 16 + l15) * CSTR +
                                                       ((quad ^ nt) << 3)];
#pragma unroll
            for (int nt = 0; nt < 4; nt++) {
                acc[0][nt] = __builtin_amdgcn_mfma_f32_16x16x32_bf16(a0, bfr[nt], acc[0][nt], 0, 0, 0);
                acc[1][nt] = __builtin_amdgcn_mfma_f32_16x16x32_bf16(a1, bfr[nt], acc[1][nt], 0, 0, 0);
            }
            pbuf ^= 1;
        }
        if (c < 7) {
            // all chunk-c gathers completed before last step's barrier
#pragma unroll
            for (int i = 0; i < 16; i++) {
                const int idx = i * 512 + t;
                const int p = idx >> 8, sl = (idx >> 4) & 15, qq = idx & 15;
                *(float4*)&s_in[p * 1024 + sl * 64 + qq * 4] = st[i];
            }
            __syncthreads();
        }
    }

    // ---- epilogue: bias, store, GN partial stats ----
    float gs[2], gq[2];
#pragma unroll
    for (int i = 0; i < 2; i++) {
        float s = 0.f, qq = 0.f;
        const int ob = wv * 32 + i * 16 + quad * 4;
#pragma unroll
        for (int reg = 0; reg < 4; reg++) {
            const int o = ob + reg;
            const float bv = bias[o];
            float* op = out + ((size_t)(b * 256 + o)) * HW + h * Ww + l15;
#pragma unroll
            for (int nt = 0; nt < 4; nt++) {
                const float v = acc[i][nt][reg] + bv;
                op[nt * 16] = v;
                s += v;
                qq += v * v;
            }
        }
        gs[i] = s; gq[i] = qq;
    }
#pragma unroll
    for (int off = 32; off; off >>= 1) {
        gs[0] += __shfl_xor(gs[0], off);
        gq[0] += __shfl_xor(gq[0], off);
        gs[1] += __shfl_xor(gs[1], off);
        gq[1] += __shfl_xor(gq[1], off);
    }
    if (lane == 0) {
#pragma unroll
        for (int i = 0; i < 2; i++) {
            const int g = wv * 2 + i;
            atomicAdd(&stats[((size_t)b * NG + g) * 2],     gs[i]);
            atomicAdd(&stats[((size_t)b * NG + g) * 2 + 1], gq[i]);
        }
    }
}

// ---------------------------------------------------------------------------
// Kernel 3: GN apply (mu/rsqrt from accumulated sums, in place)
// ---------------------------------------------------------------------------
__global__ void gn_apply_kernel(float* __restrict__ x, const float* __restrict__ stats,
                                const float* __restrict__ gamma,
                                const float* __restrict__ beta) {
    const int i = blockIdx.x * 256 + threadIdx.x;      // float4 idx, 1048576 total
    const int plane = i >> 10;                         // b*256 + o
    const int o = plane & 255;
    const int bg = plane >> 4;                         // b*16 + g
    const float s = stats[bg * 2], qv = stats[bg * 2 + 1];
    const float inv_n = 1.f / 65536.f;
    const float mu = s * inv_n;
    const float var = qv * inv_n - mu * mu;
    const float rs = rsqrtf(var + EPSV);
    const float ga = gamma[o] * rs;
    const float be = beta[o] - mu * ga;
    float4 v = ((float4*)x)[i];
    v.x = v.x * ga + be;
    v.y = v.y * ga + be;
    v.z = v.z * ga + be;
    v.w = v.w * ga + be;
    ((float4*)x)[i] = v;
}

// ---------------------------------------------------------------------------
extern "C" void kernel_launch(void* const* d_in, const int* in_sizes, int n_in,
                              void* d_out, int out_size, void* d_ws, size_t ws_size,
                              hipStream_t stream) {
    const float* input  = (const float*)d_in[0];
    const float* offset = (const float*)d_in[1];
    const float* maskp  = (const float*)d_in[2];
    const float* weight = (const float*)d_in[3];
    const float* bias   = (const float*)d_in[4];
    const float* gamma  = (const float*)d_in[5];
    const float* beta   = (const float*)d_in[6];
    float* out = (float*)d_out;

    ushort* wtb  = (ushort*)d_ws;                           // 1.18 MB
    float* stats = (float*)((char*)d_ws + (size_t)Cout * Cin * 9 * sizeof(ushort));

    hipLaunchKernelGGL(wt_kernel, dim3((Cout * Cin * 9 + 255) / 256), dim3(256), 0,
                       stream, weight, wtb, stats);
    hipLaunchKernelGGL(dcn_kernel, dim3(Bsz * Hh), dim3(512), 0, stream,
                       input, offset, maskp, wtb, bias, out, stats);
    hipLaunchKernelGGL(gn_apply_kernel, dim3((Bsz * Cout * HW / 4) / 256), dim3(256), 0,
                       stream, out, stats, gamma, beta);
}

// Round 7
// 258.936 us; speedup vs baseline: 1.1212x; 1.1212x over previous
//
#include <hip/hip_runtime.h>

typedef __attribute__((ext_vector_type(8))) short short8;   // 8 x bf16 (4 VGPR)
typedef __attribute__((ext_vector_type(4))) float f32x4;

#define Bsz 4
#define Cin 256
#define Cout 256
#define Hh 64
#define Ww 64
#define HW 4096
#define NG 16
#define EPSV 1e-5f

#define CSTR 40   // col LDS row stride in ushorts: 32 data + 8 pad (80 B, 16B-aligned)

static __device__ __forceinline__ unsigned f2bf(float f) {
    unsigned u = __float_as_uint(f);
    return (u + 0x7fffu + ((u >> 16) & 1u)) >> 16;   // RNE bf16
}

// ---------------------------------------------------------------------------
// Kernel 0: transpose input [b][c][y][x] -> in_t [b][y][x][c]
// block = 256 thr handles one (b, y, 64-channel tile): 64c x 64x slice.
// ---------------------------------------------------------------------------
__global__ void tr_kernel(const float* __restrict__ in, float* __restrict__ in_t) {
    __shared__ float tile[64 * 68];            // [c][x], pad 4
    const int bx = blockIdx.x;                 // b*256 + y*4 + ct
    const int b  = bx >> 8;
    const int y  = (bx >> 2) & 63;
    const int c0 = (bx & 3) * 64;
    const int t  = threadIdx.x;
    const int xr = (t & 15) * 4, cr = t >> 4;  // read role
#pragma unroll
    for (int j = 0; j < 4; j++) {
        const int c = cr + j * 16;
        const float4 v = *(const float4*)(in + ((size_t)(b * 256 + c0 + c)) * HW + y * 64 + xr);
        *(float4*)&tile[c * 68 + xr] = v;
    }
    __syncthreads();
    const int cw = (t & 15) * 4, xw = t >> 4;  // write role
#pragma unroll
    for (int j = 0; j < 4; j++) {
        const int x = xw + j * 16;
        float4 v;
        v.x = tile[(cw + 0) * 68 + x];
        v.y = tile[(cw + 1) * 68 + x];
        v.z = tile[(cw + 2) * 68 + x];
        v.w = tile[(cw + 3) * 68 + x];
        *(float4*)(in_t + ((size_t)b * HW + y * 64 + x) * 256 + c0 + cw) = v;
    }
}

// ---------------------------------------------------------------------------
// Kernel 1: weight reorder w[o][c][kk] -> bf16 wtb[ks][o][32],  ks = kk*8 + c/32
// Also zeroes the GN stats accumulators.
// ---------------------------------------------------------------------------
__global__ void wt_kernel(const float* __restrict__ w, ushort* __restrict__ wtb,
                          float* __restrict__ stats) {
    const int i = blockIdx.x * 256 + threadIdx.x;      // over 589824
    if (blockIdx.x == 0 && threadIdx.x < 128) stats[threadIdx.x] = 0.f;
    if (i >= Cout * Cin * 9) return;
    const int o = i / (Cin * 9);
    const int rem = i % (Cin * 9);
    const int c = rem / 9, kk = rem % 9;
    const int ks = kk * 8 + (c >> 5);
    wtb[(ks * 256 + o) * 32 + (c & 31)] = (ushort)f2bf(w[i]);
}

// ---------------------------------------------------------------------------
// Kernel 2: fused deformable sampling + bf16 MFMA conv + GN partial stats.
// Block: 512 thr (8 waves) = one row (b,h): N=64 px, M=256 Co. Grid 256.
// Input is pixel-major in_t: a bilinear corner for 4 consecutive channels is
// one float4; gather threads (px, cq) produce fully-coalesced 128B bursts.
// 2-step-deep gather prefetch + 1-step A prefetch; one barrier per K-step.
// ---------------------------------------------------------------------------
__launch_bounds__(512, 2)
__global__ void dcn_kernel(const float* __restrict__ in_t,
                           const float* __restrict__ offs,
                           const float* __restrict__ mask,
                           const ushort* __restrict__ wtb,
                           const float* __restrict__ bias,
                           float* __restrict__ out,
                           float* __restrict__ stats) {
    __shared__ ushort s_col[2][64 * CSTR];   // 10 KB double-buffered col tile
    __shared__ int2   s_ta[9 * 64];          // [k][px]: corner pixel idx (y*64+xb)
    __shared__ f32x4  s_tw[9 * 64];          // [k][px]: folded pair weights

    const int t  = threadIdx.x;
    const int bx = blockIdx.x;
    // XCD swizzle: XCD (bx&7) serves one (batch, h-half)
    const int q  = bx & 7, r = bx >> 3;
    const int b  = q >> 1;
    const int h  = ((q & 1) << 5) | r;
    const int lane = t & 63;
    const int wv   = t >> 6;                 // wave 0..7 (m-strip 32*wv)
    const int quad = lane >> 4;
    const int l15  = lane & 15;
    const int px   = t >> 3;                 // gather pixel 0..63
    const int cq   = t & 7;                  // gather channel quad (4 ch)

    // ---- tap precompute: 9 kernel points x 64 pixels ----
    for (int j = t; j < 576; j += 512) {
        const int k = j >> 6, p = j & 63;
        const float* ob = offs + (size_t)b * 18 * HW + h * Ww + p;
        const float dy = ob[(2 * k) * HW];
        const float dx = ob[(2 * k + 1) * HW];
        const float m  = mask[((size_t)b * 9 + k) * HW + h * Ww + p];
        const float y = (float)h + (float)(k / 3 - 1) + dy;
        const float x = (float)p + (float)(k % 3 - 1) + dx;
        const float y0f = floorf(y), x0f = floorf(x);
        const float ly = y - y0f, lx = x - x0f;
        const float hy = 1.f - ly, hx = 1.f - lx;
        const int y0 = (int)y0f, x0 = (int)x0f;
        const int yc0 = min(max(y0, 0), 63);
        const int yc1 = min(max(y0 + 1, 0), 63);
        const int xb  = min(max(x0, 0), 62);
        float ax = 0.f, ay = 0.f;
        if (x0 == xb) {                       // x0 in [0,62]
            ax = hx; ay = lx;
        } else if (x0 < xb) {                 // x0 < 0
            ax = (x0 + 1 == 0) ? lx : 0.f;
        } else {                              // x0 > 62
            ay = (x0 == 63) ? hx : 0.f;       // x0>=64: both corners OOB
        }
        const float w0 = (y0 >= 0 && y0 < 64) ? m * hy : 0.f;
        const float w1 = (y0 + 1 >= 0 && y0 + 1 < 64) ? m * ly : 0.f;
        s_ta[j] = make_int2(yc0 * 64 + xb, yc1 * 64 + xb);
        s_tw[j] = (f32x4){w0 * ax, w0 * ay, w1 * ax, w1 * ay};
    }
    __syncthreads();

    // ---- preload this gather thread's 9 taps into registers ----
    int2  rta[9];
    f32x4 rtw[9];
#pragma unroll
    for (int k = 0; k < 9; k++) {
        rta[k] = s_ta[k * 64 + px];
        rtw[k] = s_tw[k * 64 + px];
    }

    f32x4 acc[2][4];
#pragma unroll
    for (int i = 0; i < 2; i++)
#pragma unroll
        for (int nt = 0; nt < 4; nt++) acc[i][nt] = (f32x4){0.f, 0.f, 0.f, 0.f};

    const float* base_t = in_t + (size_t)b * (HW * 256) + cq * 4;

    // corner loads for step (chunk cc, tap kk): 4 float4 (coalesced 128B bursts)
#define GISSUE(cc, kk, gg)                                        \
    {                                                             \
        const int2 ad = rta[kk];                                  \
        const float* p0 = base_t + (size_t)ad.x * 256 + (cc) * 32;\
        const float* p1 = base_t + (size_t)ad.y * 256 + (cc) * 32;\
        gg[0] = *(const f32x4*)p0;                                \
        gg[1] = *(const f32x4*)(p0 + 256);                        \
        gg[2] = *(const f32x4*)p1;                                \
        gg[3] = *(const f32x4*)(p1 + 256);                        \
    }

    f32x4 g[2][4];
    GISSUE(0, 0, g[0]);                      // prologue: steps 0,1
    GISSUE(0, 1, g[1]);

    short8 a0c, a1c, a0n, a1n;
    {   // A prologue (ks=0)
        const ushort* wp = wtb + ((size_t)(wv * 32 + l15)) * 32 + quad * 8;
        a0c = *(const short8*)wp;
        a1c = *(const short8*)(wp + 16 * 32);
    }

#pragma unroll 1
    for (int c = 0; c < 8; c++) {
#pragma unroll 1
        for (int kk = 0; kk < 9; kk++) {
            const int s  = c * 9 + kk;
            const int pb = s & 1;
            // consume prefetched corners -> pack bf16 col slice -> publish
            {
                const f32x4 tw = rtw[kk];
                float vv[4];
#pragma unroll
                for (int j = 0; j < 4; j++)
                    vv[j] = tw[0] * g[pb][0][j] + tw[1] * g[pb][1][j] +
                            tw[2] * g[pb][2][j] + tw[3] * g[pb][3][j];
                const unsigned pk0 = f2bf(vv[0]) | (f2bf(vv[1]) << 16);
                const unsigned pk1 = f2bf(vv[2]) | (f2bf(vv[3]) << 16);
                *(unsigned long long*)&s_col[pb][px * CSTR + cq * 4] =
                    (unsigned long long)pk0 | ((unsigned long long)pk1 << 32);
            }
            __syncthreads();

            // gather prefetch for step s+2 (reuses just-consumed buffer)
            if (s < 70) {
                int kk2 = kk + 2, c2 = c;
                if (kk2 >= 9) { kk2 -= 9; c2++; }
                GISSUE(c2, kk2, g[pb]);
            }
            // A prefetch for step s+1
            if (s < 71) {
                int kk1 = kk + 1, c1 = c;
                if (kk1 >= 9) { kk1 = 0; c1++; }
                const int ks1 = kk1 * 8 + c1;
                const ushort* wp = wtb + ((size_t)(ks1 * 256 + wv * 32 + l15)) * 32 + quad * 8;
                a0n = *(const short8*)wp;
                a1n = *(const short8*)(wp + 16 * 32);
            }

            // B-frags from LDS + MFMA
            short8 bfr[4];
#pragma unroll
            for (int nt = 0; nt < 4; nt++)
                bfr[nt] = *(const short8*)&s_col[pb][(nt * 16 + l15) * CSTR + quad * 8];
#pragma unroll
            for (int nt = 0; nt < 4; nt++) {
                acc[0][nt] = __builtin_amdgcn_mfma_f32_16x16x32_bf16(a0c, bfr[nt], acc[0][nt], 0, 0, 0);
                acc[1][nt] = __builtin_amdgcn_mfma_f32_16x16x32_bf16(a1c, bfr[nt], acc[1][nt], 0, 0, 0);
            }
            a0c = a0n;
            a1c = a1n;
        }
    }
#undef GISSUE

    // ---- epilogue: bias, store, GN partial stats ----
    float gs[2], gq[2];
#pragma unroll
    for (int i = 0; i < 2; i++) {
        float sgn = 0.f, qq = 0.f;
        const int ob = wv * 32 + i * 16 + quad * 4;
#pragma unroll
        for (int reg = 0; reg < 4; reg++) {
            const int o = ob + reg;
            const float bv = bias[o];
            float* op = out + ((size_t)(b * 256 + o)) * HW + h * Ww + l15;
#pragma unroll
            for (int nt = 0; nt < 4; nt++) {
                const float v = acc[i][nt][reg] + bv;
                op[nt * 16] = v;
                sgn += v;
                qq += v * v;
            }
        }
        gs[i] = sgn; gq[i] = qq;
    }
#pragma unroll
    for (int off = 32; off; off >>= 1) {
        gs[0] += __shfl_xor(gs[0], off);
        gq[0] += __shfl_xor(gq[0], off);
        gs[1] += __shfl_xor(gs[1], off);
        gq[1] += __shfl_xor(gq[1], off);
    }
    if (lane == 0) {
#pragma unroll
        for (int i = 0; i < 2; i++) {
            const int g2 = wv * 2 + i;
            atomicAdd(&stats[((size_t)b * NG + g2) * 2],     gs[i]);
            atomicAdd(&stats[((size_t)b * NG + g2) * 2 + 1], gq[i]);
        }
    }
}

// ---------------------------------------------------------------------------
// Kernel 3: GN apply (mu/rsqrt from accumulated sums, in place)
// ---------------------------------------------------------------------------
__global__ void gn_apply_kernel(float* __restrict__ x, const float* __restrict__ stats,
                                const float* __restrict__ gamma,
                                const float* __restrict__ beta) {
    const int i = blockIdx.x * 256 + threadIdx.x;      // float4 idx, 1048576 total
    const int plane = i >> 10;                         // b*256 + o
    const int o = plane & 255;
    const int bg = plane >> 4;                         // b*16 + g
    const float s = stats[bg * 2], qv = stats[bg * 2 + 1];
    const float inv_n = 1.f / 65536.f;
    const float mu = s * inv_n;
    const float var = qv * inv_n - mu * mu;
    const float rs = rsqrtf(var + EPSV);
    const float ga = gamma[o] * rs;
    const float be = beta[o] - mu * ga;
    float4 v = ((float4*)x)[i];
    v.x = v.x * ga + be;
    v.y = v.y * ga + be;
    v.z = v.z * ga + be;
    v.w = v.w * ga + be;
    ((float4*)x)[i] = v;
}

// ---------------------------------------------------------------------------
extern "C" void kernel_launch(void* const* d_in, const int* in_sizes, int n_in,
                              void* d_out, int out_size, void* d_ws, size_t ws_size,
                              hipStream_t stream) {
    const float* input  = (const float*)d_in[0];
    const float* offset = (const float*)d_in[1];
    const float* maskp  = (const float*)d_in[2];
    const float* weight = (const float*)d_in[3];
    const float* bias   = (const float*)d_in[4];
    const float* gamma  = (const float*)d_in[5];
    const float* beta   = (const float*)d_in[6];
    float* out = (float*)d_out;

    float*  in_t  = (float*)d_ws;                            // 16.78 MB
    ushort* wtb   = (ushort*)((char*)d_ws + (size_t)Bsz * Cin * HW * 4);   // 1.18 MB
    float*  stats = (float*)((char*)wtb + (size_t)Cout * Cin * 9 * 2);

    hipLaunchKernelGGL(tr_kernel, dim3(Bsz * 64 * 4), dim3(256), 0, stream,
                       input, in_t);
    hipLaunchKernelGGL(wt_kernel, dim3((Cout * Cin * 9 + 255) / 256), dim3(256), 0,
                       stream, weight, wtb, stats);
    hipLaunchKernelGGL(dcn_kernel, dim3(Bsz * Hh), dim3(512), 0, stream,
                       in_t, offset, maskp, wtb, bias, out, stats);
    hipLaunchKernelGGL(gn_apply_kernel, dim3((Bsz * Cout * HW / 4) / 256), dim3(256), 0,
                       stream, out, stats, gamma, beta);
}